// Round 1
// 442.085 us; speedup vs baseline: 1.2415x; 1.2415x over previous
//
#include <hip/hip_runtime.h>
#include <math.h>

#define T_STEPS 2048
#define BATCH   16
#define DIM     1024
#define NSTATE  64
#define NFIELD  256                      // per (t,b): [k_norm|v|q|g] x 64
#define PROJ_TSTRIDE (BATCH * NFIELD)    // 4096 floats per t
static constexpr float EPS = 1e-6f;

#define AS1 __attribute__((address_space(1)))
#define AS3 __attribute__((address_space(3)))

typedef _Float16 f16x8 __attribute__((ext_vector_type(8)));
typedef float    f32x4 __attribute__((ext_vector_type(4)));

// ========================= projection GEMM (fp16 MFMA) =========================
// proj[m][0:64]=k_norm  [64:128]=v  [128:192]=q  [192:256]=sigmoid(beta)
// C(32768x256) = x(32768x1024) . W^T ; W rows packed [Wk|Wv|Wq|Wb].
//
// Block tile 128x256 (BN = full width -> x read exactly once, epilogue local).
// 8 waves (2m x 4n), wave tile 64x64, mfma_f32_16x16x32_f16, K-step 64.
// LDS layout is fragment-linear: one 16x32 subtile = 1024B, lane l owns bytes
// [l*16, l*16+16) = 8 contiguous-k halves (A: row=l&15, k=(l>>4)*8+j ;
// B: col=l&15, k=(l>>4)*8+j). All LDS traffic is b128 at lane*16 (conflict-free).
// Staging: global fp32 -> regs (issued before MFMA phase) -> cvt -> LDS fp16.
// Double-buffered, one barrier per K-step.

__device__ __forceinline__ f16x8 cvt8(const float4 a, const float4 b) {
    f16x8 r;
    r[0] = (_Float16)a.x; r[1] = (_Float16)a.y;
    r[2] = (_Float16)a.z; r[3] = (_Float16)a.w;
    r[4] = (_Float16)b.x; r[5] = (_Float16)b.y;
    r[6] = (_Float16)b.z; r[7] = (_Float16)b.w;
    return r;
}

#define PBM   128
#define KSTEP 64
#define NKS   (DIM / KSTEP)   // 16

__global__ __launch_bounds__(512, 2) void proj_mfma(
    const float* __restrict__ x,
    const float* __restrict__ Wk, const float* __restrict__ Wv,
    const float* __restrict__ Wq, const float* __restrict__ Wb,
    const float* __restrict__ bb,
    float* __restrict__ proj)
{
    __shared__ _Float16 Asub[2][16][64][8];   // [buf][st=kc*8+rg ][lane][j] 16KB/buf
    __shared__ _Float16 Bsub[2][32][64][8];   // [buf][st=kc*16+cg][lane][j] 32KB/buf

    const int tid = threadIdx.x;
    const int w   = tid >> 6, wl = tid & 63;
    const int wm  = w >> 2,  wn = w & 3;
    const int l15 = wl & 15, lr = wl >> 4;
    const size_t mbase = (size_t)blockIdx.x * PBM;

    // ---- staging address bases (advance by KSTEP each step) ----
    // A: 2 jobs/thread, job j covers subtile st = w + 8*j (wave-uniform st).
    const float* apA[2];
    #pragma unroll
    for (int j = 0; j < 2; ++j) {
        const int st = w + 8 * j, rg = st & 7, kc = st >> 3;
        apA[j] = x + (mbase + rg * 16 + l15) * DIM + kc * 32 + lr * 8;
    }
    // B: 4 jobs/thread, job j covers subtile st = w + 8*j.
    const float* apB[4];
    #pragma unroll
    for (int j = 0; j < 4; ++j) {
        const int st = w + 8 * j, cg = st & 15, kcb = st >> 4;
        const int col = cg * 16 + l15, field = cg >> 2, wrow = col & 63;
        const float* Wf = (field == 0 ? Wk : field == 1 ? Wv : field == 2 ? Wq : Wb);
        apB[j] = Wf + (size_t)wrow * DIM + kcb * 32 + lr * 8;
    }

    float4 hA[2][2], hB[4][2];
    auto load_regs = [&](int ks) {
        const int k0 = ks * KSTEP;
        #pragma unroll
        for (int j = 0; j < 2; ++j) {
            hA[j][0] = *(const float4*)(apA[j] + k0);
            hA[j][1] = *(const float4*)(apA[j] + k0 + 4);
        }
        #pragma unroll
        for (int j = 0; j < 4; ++j) {
            hB[j][0] = *(const float4*)(apB[j] + k0);
            hB[j][1] = *(const float4*)(apB[j] + k0 + 4);
        }
    };
    auto write_lds = [&](int buf) {
        #pragma unroll
        for (int j = 0; j < 2; ++j)
            *(f16x8*)&Asub[buf][w + 8 * j][wl][0] = cvt8(hA[j][0], hA[j][1]);
        #pragma unroll
        for (int j = 0; j < 4; ++j)
            *(f16x8*)&Bsub[buf][w + 8 * j][wl][0] = cvt8(hB[j][0], hB[j][1]);
    };

    f32x4 acc[4][4] = {};

    load_regs(0);
    write_lds(0);
    __syncthreads();

    for (int ks = 0; ks < NKS; ++ks) {
        const int buf = ks & 1;
        if (ks + 1 < NKS) load_regs(ks + 1);   // in flight across MFMA phase

        #pragma unroll
        for (int kc = 0; kc < 2; ++kc) {
            f16x8 af[4], bf[4];
            #pragma unroll
            for (int mf = 0; mf < 4; ++mf)
                af[mf] = *(const f16x8*)&Asub[buf][kc * 8 + wm * 4 + mf][wl][0];
            #pragma unroll
            for (int nf = 0; nf < 4; ++nf)
                bf[nf] = *(const f16x8*)&Bsub[buf][kc * 16 + wn * 4 + nf][wl][0];
            #pragma unroll
            for (int mf = 0; mf < 4; ++mf)
                #pragma unroll
                for (int nf = 0; nf < 4; ++nf)
                    acc[mf][nf] = __builtin_amdgcn_mfma_f32_16x16x32_f16(
                        af[mf], bf[nf], acc[mf][nf], 0, 0, 0);
        }

        if (ks + 1 < NKS) write_lds(buf ^ 1);
        __syncthreads();
    }

    // ---- fused epilogue ----
    // D frag layout: col = lane&15, row = (lane>>4)*4 + r  [m89-verified]
    if (wn == 0) {                       // k field: row-normalize over 64 cols
        #pragma unroll
        for (int mf = 0; mf < 4; ++mf) {
            f32x4 s = acc[mf][0] * acc[mf][0];
            #pragma unroll
            for (int nf = 1; nf < 4; ++nf) s += acc[mf][nf] * acc[mf][nf];
            #pragma unroll
            for (int r = 0; r < 4; ++r) {
                float t = s[r];
                t += __shfl_xor(t, 1); t += __shfl_xor(t, 2);
                t += __shfl_xor(t, 4); t += __shfl_xor(t, 8);
                const float sc = 1.f / (sqrtf(t) + EPS);
                #pragma unroll
                for (int nf = 0; nf < 4; ++nf) acc[mf][nf][r] *= sc;
            }
        }
    }
    if (wn == 3) {                       // beta field: sigmoid(acc + bias)
        #pragma unroll
        for (int nf = 0; nf < 4; ++nf) {
            const float bv = bb[nf * 16 + l15];
            #pragma unroll
            for (int mf = 0; mf < 4; ++mf)
                #pragma unroll
                for (int r = 0; r < 4; ++r)
                    acc[mf][nf][r] = 1.f / (1.f + __expf(-(acc[mf][nf][r] + bv)));
        }
    }

    #pragma unroll
    for (int mf = 0; mf < 4; ++mf)
        #pragma unroll
        for (int r = 0; r < 4; ++r) {
            float* dst = proj + (mbase + wm * 64 + mf * 16 + lr * 4 + r) * NFIELD
                              + wn * 64 + l15;
            dst[0]  = acc[mf][0][r];
            dst[16] = acc[mf][1][r];
            dst[32] = acc[mf][2][r];
            dst[48] = acc[mf][3][r];
        }
}

// ============================ sequential scan v5 ============================
// (unchanged — DMA staging via global_load_lds, depth-4 rotating slots)

template <int CTRL>
__device__ __forceinline__ float dpp_add(float x) {
    int yi = __builtin_amdgcn_update_dpp(0, __float_as_int(x), CTRL, 0xF, 0xF, true);
    return x + __int_as_float(yi);
}
__device__ __forceinline__ float reduce16(float x) {
    x = dpp_add<0x121>(x);   // row_ror:1
    x = dpp_add<0x122>(x);   // row_ror:2
    x = dpp_add<0x124>(x);   // row_ror:4
    x = dpp_add<0x128>(x);   // row_ror:8
    return x;
}
__device__ __forceinline__ float dot4r(const float4& u, const float4& w) {
    float t0 = u.x * w.x; t0 = fmaf(u.y, w.y, t0);
    float t1 = u.z * w.z; t1 = fmaf(u.w, w.w, t1);
    return reduce16(t0 + t1);
}

#define CH 32
#define NCHUNK (T_STEPS / CH)

__global__ __launch_bounds__(128) void scan_kernel(
    const float* __restrict__ proj,  // [T][B][256]
    const float* __restrict__ S0,    // [B][64][64]
    float* __restrict__ out,         // [T][B][64]  (raw Sq; silu applied later)
    float* __restrict__ Sfin)        // [B][64][64]
{
    __shared__ float KQ[2][CH][128];   // [s][0:64)=kn, [64:128)=q   (32 KB)
    __shared__ float VG[2][CH][16];    // [s][2r]=v(i0+r), [s][2r+1]=g(i0+r)

    const int tid = threadIdx.x;          // 0..127
    const int l   = tid & 15;
    const int grp = tid >> 4;             // 0..7 -> row within block
    const int b   = blockIdx.x >> 3;
    const int i0  = (blockIdx.x & 7) * 8;
    const int i   = i0 + grp;
    const int c0  = l * 4;

    const size_t srow = ((size_t)(b * 64 + i)) * 64 + c0;
    float4 S = *(const float4*)(S0 + srow);

    const float* pb = proj + (size_t)b * NFIELD;
    const int wid = tid >> 6, wl = tid & 63;

    // --- DMA address maps (constant per lane) ---
    const int l31  = wl & 31;
    const int kq_f = l31 * 4 + ((l31 >= 16) ? 64 : 0);
    const int kq_s = wl >> 5;
    const int idx  = wl & 15;
    const int vg_f = (idx & 1) ? (192 + i0 + (idx >> 1)) : (64 + i0 + (idx >> 1));
    const int vg_s = wl >> 4;

    auto stage = [&](int c, int nb) {
        const float* cbase = pb + (size_t)c * CH * PROJ_TSTRIDE;
        #pragma unroll
        for (int m = 0; m < 8; ++m) {                    // 16 KQ insts over 2 waves
            const int n = wid * 8 + m;
            const float* g = cbase + (size_t)(2 * n + kq_s) * PROJ_TSTRIDE + kq_f;
            void* lp = (char*)&KQ[nb][0][0] + n * 1024;
            __builtin_amdgcn_global_load_lds((const AS1 void*)g, (AS3 void*)lp, 16, 0, 0);
        }
        #pragma unroll
        for (int m = 0; m < 4; ++m) {                    // 8 VG insts over 2 waves
            const int p = wid * 4 + m;
            const float* g = cbase + (size_t)(4 * p + vg_s) * PROJ_TSTRIDE + vg_f;
            void* lp = (char*)&VG[nb][0][0] + p * 256;
            __builtin_amdgcn_global_load_lds((const AS1 void*)g, (AS3 void*)lp, 4, 0, 0);
        }
    };

    float4 kn_s[4], q_s[4];
    float2 vg_s4[4];
    auto ldslot = [&](int cb, int s, int j) {
        kn_s[j]  = *(const float4*)(&KQ[cb][s][c0]);
        q_s[j]   = *(const float4*)(&KQ[cb][s][64 + c0]);
        vg_s4[j] = *(const float2*)(&VG[cb][s][2 * grp]);
    };

    stage(0, 0);
    __syncthreads();                     // waits DMA (vmcnt) + all threads

    float a;
    auto prime = [&](int nb) {
        #pragma unroll
        for (int j = 0; j < 4; ++j) ldslot(nb, j, j);
        a = dot4r(S, kn_s[0]);           // recompute carried dot from S
    };
    prime(0);

    float osel = 0.f;

    for (int c = 0; c < NCHUNK; ++c) {
        const int cb = c & 1;
        const bool more = (c + 1 < NCHUNK);
        if (more) stage(c + 1, cb ^ 1);  // DMA in flight across this chunk

        #pragma unroll
        for (int s = 0; s < CH; ++s) {
            const int j = s & 3;
            const float4 kn = kn_s[j], q = q_s[j];
            const float  v = vg_s4[j].x, g = vg_s4[j].y;

            if (s + 4 < CH) ldslot(cb, s + 4, j);   // refill the slot just freed

            const float d = v - a;
            S.x = fmaf(d, kn.x, g * S.x);
            S.y = fmaf(d, kn.y, g * S.y);
            S.z = fmaf(d, kn.z, g * S.z);
            S.w = fmaf(d, kn.w, g * S.w);

            const float sq = dot4r(S, q);
            if (s + 1 < CH) a = dot4r(S, kn_s[(s + 1) & 3]);

            osel = ((s & 15) == l) ? sq : osel;
            if ((s & 15) == 15) {
                const int tbase = c * CH + (s - 15);
                out[((size_t)(tbase + l) * BATCH + b) * 64 + i] = osel;
            }
        }

        if (more) {
            __syncthreads();             // next chunk's DMA complete
            prime(cb ^ 1);
        }
    }

    *(float4*)(Sfin + srow) = S;
}

// ============================ silu post-kernel ============================
__global__ __launch_bounds__(256) void silu_kernel(float* __restrict__ out) {
    const int idx = blockIdx.x * 256 + threadIdx.x;
    float4* p = (float4*)out + idx;
    float4 x = *p;
    x.x = x.x * x.x / (1.f + __expf(-x.x));
    x.y = x.y * x.y / (1.f + __expf(-x.y));
    x.z = x.z * x.z / (1.f + __expf(-x.z));
    x.w = x.w * x.w / (1.f + __expf(-x.w));
    *p = x;
}

// ================================ launch ================================
extern "C" void kernel_launch(void* const* d_in, const int* in_sizes, int n_in,
                              void* d_out, int out_size, void* d_ws, size_t ws_size,
                              hipStream_t stream) {
    const float* x  = (const float*)d_in[0];
    const float* S0 = (const float*)d_in[1];
    const float* Wk = (const float*)d_in[2];
    const float* Wv = (const float*)d_in[3];
    const float* Wq = (const float*)d_in[4];
    const float* Wb = (const float*)d_in[5];
    const float* bb = (const float*)d_in[6];

    float* out  = (float*)d_out;                               // [T][B][64]
    float* Sfin = out + (size_t)T_STEPS * BATCH * NSTATE;      // [B][64][64]
    float* proj = (float*)d_ws;                                // [T*B][256] = 33.5 MB

    proj_mfma<<<(T_STEPS * BATCH) / PBM, 512, 0, stream>>>(x, Wk, Wv, Wq, Wb, bb, proj);
    scan_kernel<<<(BATCH * NSTATE) / 8, 128, 0, stream>>>(proj, S0, out, Sfin);
    silu_kernel<<<(T_STEPS * BATCH * NSTATE) / 4 / 256, 256, 0, stream>>>(out);
}

// Round 2
// 424.782 us; speedup vs baseline: 1.2920x; 1.0407x over previous
//
#include <hip/hip_runtime.h>
#include <math.h>

#define T_STEPS 2048
#define BATCH   16
#define DIM     1024
#define NSTATE  64
#define NFIELD  256                      // per (t,b): [k_norm|v|q|g] x 64
#define PROJ_TSTRIDE (BATCH * NFIELD)    // 4096 floats per t
static constexpr float EPS = 1e-6f;

#define AS1 __attribute__((address_space(1)))
#define AS3 __attribute__((address_space(3)))

typedef _Float16 f16x8 __attribute__((ext_vector_type(8)));
typedef _Float16 f16x4 __attribute__((ext_vector_type(4)));
typedef float    f32x4 __attribute__((ext_vector_type(4)));

// ===================== cross-lane helpers (16-lane reduce) =====================
template <int CTRL>
__device__ __forceinline__ float dpp_add(float x) {
    int yi = __builtin_amdgcn_update_dpp(0, __float_as_int(x), CTRL, 0xF, 0xF, true);
    return x + __int_as_float(yi);
}
__device__ __forceinline__ float reduce16(float x) {
    x = dpp_add<0x121>(x);   // row_ror:1
    x = dpp_add<0x122>(x);   // row_ror:2
    x = dpp_add<0x124>(x);   // row_ror:4
    x = dpp_add<0x128>(x);   // row_ror:8
    return x;
}
__device__ __forceinline__ float dot4r(const float4& u, const float4& w) {
    float t0 = u.x * w.x; t0 = fmaf(u.y, w.y, t0);
    float t1 = u.z * w.z; t1 = fmaf(u.w, w.w, t1);
    return reduce16(t0 + t1);
}

// ========================= projection GEMM (fp16 MFMA) =========================
// C(32768x256) = x(32768x1024) . W^T ; W rows packed [Wk|Wv|Wq|Wb].
// Block tile 128x256, 8 waves (2m x 4n), wave tile 64x64, mfma 16x16x32_f16.
// LDS fragment-linear: one 16x32 subtile = 1024B, lane l owns 16B
// (A: row=l&15, k=(l>>4)*8+j ; B: col=l&15, k=(l>>4)*8+j).
// B: pre-converted fp16 weights in fragment order (W16) -> global_load_lds DMA.
// A: coalesced fp32 loads (16 lanes = one contiguous 256B row run) -> cvt -> LDS.

#define PBM   128
#define KSTEP 64
#define NKS   (DIM / KSTEP)   // 16

// W16 layout: [ks][st][lane][j] halves, st = kc2*16+cg, col=cg*16+(lane&15),
// field=col>>6, wrow=col&63, k = ks*64 + kc2*32 + (lane>>4)*8 + j.
__global__ __launch_bounds__(256) void prep_w16(
    const float* __restrict__ Wk, const float* __restrict__ Wv,
    const float* __restrict__ Wq, const float* __restrict__ Wb,
    _Float16* __restrict__ W16)
{
    const int flat = blockIdx.x * 256 + threadIdx.x;   // 16*32*64 = 32768
    const int lane = flat & 63;
    const int st   = (flat >> 6) & 31;
    const int ks   = flat >> 11;
    const int cg = st & 15, kc2 = st >> 4;
    const int col = cg * 16 + (lane & 15);
    const int field = col >> 6, wrow = col & 63;
    const float* Wf = (field == 0 ? Wk : field == 1 ? Wv : field == 2 ? Wq : Wb);
    const float* src = Wf + (size_t)wrow * DIM + ks * 64 + kc2 * 32 + (lane >> 4) * 8;
    const float4 a = *(const float4*)(src);
    const float4 b = *(const float4*)(src + 4);
    f16x8 r;
    r[0] = (_Float16)a.x; r[1] = (_Float16)a.y; r[2] = (_Float16)a.z; r[3] = (_Float16)a.w;
    r[4] = (_Float16)b.x; r[5] = (_Float16)b.y; r[6] = (_Float16)b.z; r[7] = (_Float16)b.w;
    *(f16x8*)(W16 + (size_t)flat * 8) = r;
}

__global__ __launch_bounds__(512, 2) void proj_mfma(
    const float* __restrict__ x, const _Float16* __restrict__ W16,
    const float* __restrict__ bb, float* __restrict__ proj)
{
    __shared__ _Float16 Asub[2][16][64][8];   // 16KB/buf
    __shared__ _Float16 Bsub[2][32][64][8];   // 32KB/buf

    const int tid = threadIdx.x;
    const int w = tid >> 6, wl = tid & 63;
    const int wm = w >> 2, wn = w & 3;
    const int l15 = wl & 15, lr = wl >> 4;
    const size_t mbase = (size_t)blockIdx.x * PBM;

    _Float16* const abase = &Asub[0][0][0][0];
    _Float16* const bbase = &Bsub[0][0][0][0];

    // ---- A staging map: 4 float4/thread, fully coalesced ----
    // fid = it*512+tid: row = fid>>4 (16 float4 per row), kq = (fid&15)*4
    const float* asrc[4];
    int aoff[4];
    #pragma unroll
    for (int it = 0; it < 4; ++it) {
        const int fid = it * 512 + tid;
        const int row = fid >> 4, kq = (fid & 15) * 4;
        asrc[it] = x + (mbase + row) * (size_t)DIM + kq;
        aoff[it] = ((kq >> 5) * 8 + (row >> 4)) * 512          // st * 64*8
                 + ((row & 15) + ((kq >> 3) & 3) * 16) * 8     // lane_m * 8
                 + (kq & 7);                                    // j (0 or 4)
    }
    // ---- B staging map: 4 global_load_lds per wave (st wave-uniform) ----
    const _Float16* bsrc[4];
    int boff[4];
    #pragma unroll
    for (int m = 0; m < 4; ++m) {
        const int st = w * 4 + m;
        bsrc[m] = W16 + ((size_t)st * 64 + wl) * 8;   // + ks*16384 per step
        boff[m] = st * 512;                            // halves into Bsub[buf]
    }

    auto stageB = [&](int ks, int buf) {
        #pragma unroll
        for (int m = 0; m < 4; ++m) {
            const _Float16* g = bsrc[m] + (size_t)ks * 16384;
            void* lp = (char*)bbase + (size_t)(buf * 16384 + boff[m]) * 2;
            __builtin_amdgcn_global_load_lds((const AS1 void*)g, (AS3 void*)lp, 16, 0, 0);
        }
    };

    float4 ha[4];
    auto loadA = [&](int ks) {
        #pragma unroll
        for (int it = 0; it < 4; ++it)
            ha[it] = *(const float4*)(asrc[it] + ks * KSTEP);
    };
    auto writeA = [&](int buf) {
        #pragma unroll
        for (int it = 0; it < 4; ++it) {
            f16x4 h;
            h[0] = (_Float16)ha[it].x; h[1] = (_Float16)ha[it].y;
            h[2] = (_Float16)ha[it].z; h[3] = (_Float16)ha[it].w;
            *(f16x4*)(abase + buf * 8192 + aoff[it]) = h;
        }
    };

    f32x4 acc[4][4] = {};

    stageB(0, 0);
    loadA(0); writeA(0);
    __syncthreads();

    for (int ks = 0; ks < NKS; ++ks) {
        const int buf = ks & 1;
        if (ks + 1 < NKS) {
            stageB(ks + 1, buf ^ 1);     // DMA in flight across MFMA phase
            loadA(ks + 1);               // coalesced fp32 loads in flight
        }

        #pragma unroll
        for (int kc = 0; kc < 2; ++kc) {
            f16x8 af[4], bf[4];
            #pragma unroll
            for (int mf = 0; mf < 4; ++mf)
                af[mf] = *(const f16x8*)&Asub[buf][kc * 8 + wm * 4 + mf][wl][0];
            #pragma unroll
            for (int nf = 0; nf < 4; ++nf)
                bf[nf] = *(const f16x8*)&Bsub[buf][kc * 16 + wn * 4 + nf][wl][0];
            #pragma unroll
            for (int mf = 0; mf < 4; ++mf)
                #pragma unroll
                for (int nf = 0; nf < 4; ++nf)
                    acc[mf][nf] = __builtin_amdgcn_mfma_f32_16x16x32_f16(
                        af[mf], bf[nf], acc[mf][nf], 0, 0, 0);
        }

        if (ks + 1 < NKS) writeA(buf ^ 1);
        __syncthreads();
    }

    // ---- fused epilogue (D frag: col = lane&15, row = (lane>>4)*4 + r) ----
    if (wn == 0) {                       // k field: row-normalize over 64 cols
        #pragma unroll
        for (int mf = 0; mf < 4; ++mf) {
            f32x4 s = acc[mf][0] * acc[mf][0];
            #pragma unroll
            for (int nf = 1; nf < 4; ++nf) s += acc[mf][nf] * acc[mf][nf];
            #pragma unroll
            for (int r = 0; r < 4; ++r) {
                float t = s[r];
                t += __shfl_xor(t, 1); t += __shfl_xor(t, 2);
                t += __shfl_xor(t, 4); t += __shfl_xor(t, 8);
                const float sc = 1.f / (sqrtf(t) + EPS);
                #pragma unroll
                for (int nf = 0; nf < 4; ++nf) acc[mf][nf][r] *= sc;
            }
        }
    }
    if (wn == 3) {                       // beta field: sigmoid(acc + bias)
        #pragma unroll
        for (int nf = 0; nf < 4; ++nf) {
            const float bv = bb[nf * 16 + l15];
            #pragma unroll
            for (int mf = 0; mf < 4; ++mf)
                #pragma unroll
                for (int r = 0; r < 4; ++r)
                    acc[mf][nf][r] = 1.f / (1.f + __expf(-(acc[mf][nf][r] + bv)));
        }
    }

    #pragma unroll
    for (int mf = 0; mf < 4; ++mf)
        #pragma unroll
        for (int r = 0; r < 4; ++r) {
            float* dst = proj + (mbase + wm * 64 + mf * 16 + lr * 4 + r) * NFIELD
                              + wn * 64 + l15;
            dst[0]  = acc[mf][0][r];
            dst[16] = acc[mf][1][r];
            dst[32] = acc[mf][2][r];
            dst[48] = acc[mf][3][r];
        }
}

// ============================ kappa precompute ============================
// kap[t*16+b] = <k_norm(t-1,b), k_norm(t,b)>, 0 for t==0 or t>=T (pad to 2112).
#define KAP_T 2112

__global__ __launch_bounds__(256) void kappa_kernel(
    const float* __restrict__ proj, float* __restrict__ kap)
{
    const int tid = threadIdx.x;
    const int gid = blockIdx.x * 16 + (tid >> 4);   // one (t,b) per 16 lanes
    const int l   = tid & 15;
    const int t = gid >> 4, b = gid & 15;
    if (t == 0 || t >= T_STEPS) {
        if (l == 0) kap[gid] = 0.f;
        return;
    }
    const float4 u = *(const float4*)(proj + ((size_t)t * BATCH + b) * NFIELD + 4 * l);
    const float4 w = *(const float4*)(proj + ((size_t)(t - 1) * BATCH + b) * NFIELD + 4 * l);
    const float p = dot4r(u, w);
    if (l == 0) kap[gid] = p;
}

// ============================ sequential scan v6 ============================
// Look-ahead recurrence: a(t+1) = g(t)*<S(t-1),k(t+1)> + d(t)*kappa(t+1).
// The cross-lane dot (c) uses the PREVIOUS S -> one full step of slack; the
// loop-carried chain is a -> d -> fma -> a (~8 cyc). Re-anchored (full dot)
// at every chunk boundary via prime(). silu fused into the output store.

#define CH 32
#define NCHUNK (T_STEPS / CH)

__global__ __launch_bounds__(128) void scan_kernel(
    const float* __restrict__ proj,  // [T][B][256]
    const float* __restrict__ kap,   // [KAP_T][B]
    const float* __restrict__ S0,    // [B][64][64]
    float* __restrict__ out,         // [T][B][64]  (silu applied at store)
    float* __restrict__ Sfin)        // [B][64][64]
{
    __shared__ float KQ[2][CH][128];   // [s][0:64)=kn, [64:128)=q   (32 KB)
    __shared__ float VG[2][CH][16];    // [s][2r]=v(i0+r), [s][2r+1]=g(i0+r)
    __shared__ float KP[2][64];        // [e] = kappa(t0+e+1)  (DMA writes 64)

    const int tid = threadIdx.x;          // 0..127
    const int l   = tid & 15;
    const int grp = tid >> 4;             // 0..7 -> row within block
    const int b   = blockIdx.x >> 3;
    const int i0  = (blockIdx.x & 7) * 8;
    const int i   = i0 + grp;
    const int c0  = l * 4;

    const size_t srow = ((size_t)(b * 64 + i)) * 64 + c0;
    float4 S = *(const float4*)(S0 + srow);

    const float* pb = proj + (size_t)b * NFIELD;
    const int wid = tid >> 6, wl = tid & 63;

    // --- DMA address maps (constant per lane) ---
    const int l31  = wl & 31;
    const int kq_f = l31 * 4 + ((l31 >= 16) ? 64 : 0);
    const int kq_s = wl >> 5;
    const int idx  = wl & 15;
    const int vg_f = (idx & 1) ? (192 + i0 + (idx >> 1)) : (64 + i0 + (idx >> 1));
    const int vg_s = wl >> 4;

    auto stage = [&](int c, int nb) {
        const float* cbase = pb + (size_t)c * CH * PROJ_TSTRIDE;
        #pragma unroll
        for (int m = 0; m < 8; ++m) {                    // 16 KQ insts over 2 waves
            const int n = wid * 8 + m;
            const float* g = cbase + (size_t)(2 * n + kq_s) * PROJ_TSTRIDE + kq_f;
            void* lp = (char*)&KQ[nb][0][0] + n * 1024;
            __builtin_amdgcn_global_load_lds((const AS1 void*)g, (AS3 void*)lp, 16, 0, 0);
        }
        #pragma unroll
        for (int m = 0; m < 4; ++m) {                    // 8 VG insts over 2 waves
            const int p = wid * 4 + m;
            const float* g = cbase + (size_t)(4 * p + vg_s) * PROJ_TSTRIDE + vg_f;
            void* lp = (char*)&VG[nb][0][0] + p * 256;
            __builtin_amdgcn_global_load_lds((const AS1 void*)g, (AS3 void*)lp, 4, 0, 0);
        }
        if (wid == 0) {                                  // kappa(t0+1 .. t0+64)
            const float* g = kap + ((size_t)(c * CH + wl + 1) * BATCH + b);
            void* lp = (char*)&KP[nb][0];
            __builtin_amdgcn_global_load_lds((const AS1 void*)g, (AS3 void*)lp, 4, 0, 0);
        }
    };

    float4 kn_s[4], q_s[4];
    float2 vg_s4[4];
    auto ldslot = [&](int cb, int s, int j) {
        kn_s[j]  = *(const float4*)(&KQ[cb][s][c0]);
        q_s[j]   = *(const float4*)(&KQ[cb][s][64 + c0]);
        vg_s4[j] = *(const float2*)(&VG[cb][s][2 * grp]);
    };

    stage(0, 0);
    __syncthreads();                     // waits DMA (vmcnt) + all threads

    float a;
    auto prime = [&](int nb) {
        #pragma unroll
        for (int j = 0; j < 4; ++j) ldslot(nb, j, j);
        a = dot4r(S, kn_s[0]);           // full-dot re-anchor of carried a
    };
    prime(0);

    float osel = 0.f;

    for (int c = 0; c < NCHUNK; ++c) {
        const int cb = c & 1;
        const bool more = (c + 1 < NCHUNK);
        if (more) stage(c + 1, cb ^ 1);  // DMA in flight across this chunk

        #pragma unroll
        for (int s = 0; s < CH; ++s) {
            const int j = s & 3;
            const float4 kn = kn_s[j], q = q_s[j];
            const float  v = vg_s4[j].x, g = vg_s4[j].y;

            float cpart = 0.f, kap_n = 0.f;
            if (s + 1 < CH) {
                const float4 knn = kn_s[(s + 1) & 3];   // k(t+1)
                kap_n = KP[cb][s];                      // kappa(t+1)
                cpart = dot4r(S, knn);                  // <S(t-1),k(t+1)>, off-path
            }

            if (s + 4 < CH) ldslot(cb, s + 4, j);   // refill the slot just freed

            const float d = v - a;
            S.x = fmaf(d, kn.x, g * S.x);
            S.y = fmaf(d, kn.y, g * S.y);
            S.z = fmaf(d, kn.z, g * S.z);
            S.w = fmaf(d, kn.w, g * S.w);

            const float sq = dot4r(S, q);
            if (s + 1 < CH) a = fmaf(d, kap_n, g * cpart);   // a(t+1), 2-op chain

            osel = ((s & 15) == l) ? sq : osel;
            if ((s & 15) == 15) {
                const float y = osel * osel / (1.f + __expf(-osel));  // fused silu
                const int tbase = c * CH + (s - 15);
                out[((size_t)(tbase + l) * BATCH + b) * 64 + i] = y;
            }
        }

        if (more) {
            __syncthreads();             // next chunk's DMA complete
            prime(cb ^ 1);               // re-anchor a with a full dot
        }
    }

    *(float4*)(Sfin + srow) = S;
}

// ================================ launch ================================
extern "C" void kernel_launch(void* const* d_in, const int* in_sizes, int n_in,
                              void* d_out, int out_size, void* d_ws, size_t ws_size,
                              hipStream_t stream) {
    const float* x  = (const float*)d_in[0];
    const float* S0 = (const float*)d_in[1];
    const float* Wk = (const float*)d_in[2];
    const float* Wv = (const float*)d_in[3];
    const float* Wq = (const float*)d_in[4];
    const float* Wb = (const float*)d_in[5];
    const float* bb = (const float*)d_in[6];

    float* out  = (float*)d_out;                               // [T][B][64]
    float* Sfin = out + (size_t)T_STEPS * BATCH * NSTATE;      // [B][64][64]

    float*    proj = (float*)d_ws;                             // 33.55 MB
    float*    kap  = proj + (size_t)T_STEPS * BATCH * NFIELD;  // 132 KB (padded)
    _Float16* W16  = (_Float16*)(kap + (size_t)KAP_T * BATCH); // 512 KB

    prep_w16<<<128, 256, 0, stream>>>(Wk, Wv, Wq, Wb, W16);
    proj_mfma<<<(T_STEPS * BATCH) / PBM, 512, 0, stream>>>(x, W16, bb, proj);
    kappa_kernel<<<KAP_T, 256, 0, stream>>>(proj, kap);
    scan_kernel<<<(BATCH * NSTATE) / 8, 128, 0, stream>>>(proj, kap, S0, out, Sfin);
}

// Round 5
// 422.554 us; speedup vs baseline: 1.2988x; 1.0053x over previous
//
#include <hip/hip_runtime.h>
#include <math.h>

#define T_STEPS 2048
#define BATCH   16
#define DIM     1024
#define NSTATE  64
#define NFIELD  256                      // per (t,b): [k_norm|v|q|g] x 64
#define PROJ_TSTRIDE (BATCH * NFIELD)    // 4096 floats per t
static constexpr float EPS = 1e-6f;

#define AS1 __attribute__((address_space(1)))
#define AS3 __attribute__((address_space(3)))

typedef _Float16 f16x8 __attribute__((ext_vector_type(8)));
typedef _Float16 f16x4 __attribute__((ext_vector_type(4)));
typedef float    f32x4 __attribute__((ext_vector_type(4)));

// ===================== cross-lane helpers (16-lane reduce) =====================
template <int CTRL>
__device__ __forceinline__ float dpp_add(float x) {
    int yi = __builtin_amdgcn_update_dpp(0, __float_as_int(x), CTRL, 0xF, 0xF, true);
    return x + __int_as_float(yi);
}
__device__ __forceinline__ float reduce16(float x) {
    x = dpp_add<0x121>(x);   // row_ror:1
    x = dpp_add<0x122>(x);   // row_ror:2
    x = dpp_add<0x124>(x);   // row_ror:4
    x = dpp_add<0x128>(x);   // row_ror:8
    return x;
}
// interleaved dual reduce: the two DPP chains fill each other's dep gaps
__device__ __forceinline__ void reduce16x2(float& x, float& y) {
    x = dpp_add<0x121>(x); y = dpp_add<0x121>(y);
    x = dpp_add<0x122>(x); y = dpp_add<0x122>(y);
    x = dpp_add<0x124>(x); y = dpp_add<0x124>(y);
    x = dpp_add<0x128>(x); y = dpp_add<0x128>(y);
}
__device__ __forceinline__ float dot4r(const float4& u, const float4& w) {
    float t0 = u.x * w.x; t0 = fmaf(u.y, w.y, t0);
    float t1 = u.z * w.z; t1 = fmaf(u.w, w.w, t1);
    return reduce16(t0 + t1);
}

// ========================= projection GEMM (fp16 MFMA) =========================
// Block tile 128x256, 8 waves (2m x 4n), wave tile 64x64, mfma 16x16x32_f16.
// LDS fragment-linear (lane*16B b128, conflict-free). B via global_load_lds DMA
// of pre-converted fragment-ordered fp16 weights. A: coalesced fp32 loads,
// 2 K-iterations deep (reg double-buffer h0/h1). K-loop fully unrolled so all
// register-array indices are static.

#define PBM   128
#define KSTEP 64
#define NKS   (DIM / KSTEP)   // 16

__global__ __launch_bounds__(256) void prep_w16(
    const float* __restrict__ Wk, const float* __restrict__ Wv,
    const float* __restrict__ Wq, const float* __restrict__ Wb,
    _Float16* __restrict__ W16)
{
    const int flat = blockIdx.x * 256 + threadIdx.x;   // 16*32*64 = 32768
    const int lane = flat & 63;
    const int st   = (flat >> 6) & 31;
    const int ks   = flat >> 11;
    const int cg = st & 15, kc2 = st >> 4;
    const int col = cg * 16 + (lane & 15);
    const int field = col >> 6, wrow = col & 63;
    const float* Wf = (field == 0 ? Wk : field == 1 ? Wv : field == 2 ? Wq : Wb);
    const float* src = Wf + (size_t)wrow * DIM + ks * 64 + kc2 * 32 + (lane >> 4) * 8;
    const float4 a = *(const float4*)(src);
    const float4 b = *(const float4*)(src + 4);
    f16x8 r;
    r[0] = (_Float16)a.x; r[1] = (_Float16)a.y; r[2] = (_Float16)a.z; r[3] = (_Float16)a.w;
    r[4] = (_Float16)b.x; r[5] = (_Float16)b.y; r[6] = (_Float16)b.z; r[7] = (_Float16)b.w;
    *(f16x8*)(W16 + (size_t)flat * 8) = r;
}

__global__ __launch_bounds__(512) void proj_mfma(
    const float* __restrict__ x, const _Float16* __restrict__ W16,
    const float* __restrict__ bb, float* __restrict__ proj)
{
    __shared__ _Float16 Asub[2][16][64][8];   // 16KB/buf
    __shared__ _Float16 Bsub[2][32][64][8];   // 32KB/buf

    const int tid = threadIdx.x;
    const int w = tid >> 6, wl = tid & 63;
    const int wm = w >> 2, wn = w & 3;
    const int l15 = wl & 15, lr = wl >> 4;
    const size_t mbase = (size_t)blockIdx.x * PBM;

    _Float16* const abase = &Asub[0][0][0][0];
    _Float16* const bbase = &Bsub[0][0][0][0];

    // ---- A staging map: 4 float4/thread, fully coalesced ----
    const float* asrc[4];
    int aoff[4];
    #pragma unroll
    for (int it = 0; it < 4; ++it) {
        const int fid = it * 512 + tid;
        const int row = fid >> 4, kq = (fid & 15) * 4;
        asrc[it] = x + (mbase + row) * (size_t)DIM + kq;
        aoff[it] = ((kq >> 5) * 8 + (row >> 4)) * 512
                 + ((row & 15) + ((kq >> 3) & 3) * 16) * 8
                 + (kq & 7);
    }
    // ---- B staging map: 4 global_load_lds per wave (st wave-uniform) ----
    const _Float16* bsrc[4];
    int boff[4];
    #pragma unroll
    for (int m = 0; m < 4; ++m) {
        const int st = w * 4 + m;
        bsrc[m] = W16 + ((size_t)st * 64 + wl) * 8;
        boff[m] = st * 512;
    }

    auto stageB = [&](int ks, int buf) {
        #pragma unroll
        for (int m = 0; m < 4; ++m) {
            const _Float16* g = bsrc[m] + (size_t)ks * 16384;
            void* lp = (char*)bbase + (size_t)(buf * 16384 + boff[m]) * 2;
            __builtin_amdgcn_global_load_lds((const AS1 void*)g, (AS3 void*)lp, 16, 0, 0);
        }
    };

    float4 h0[4], h1[4];
    auto loadA = [&](int ks, float4* h) {
        #pragma unroll
        for (int it = 0; it < 4; ++it)
            h[it] = *(const float4*)(asrc[it] + ks * KSTEP);
    };
    auto writeA = [&](const float4* h, int buf) {
        #pragma unroll
        for (int it = 0; it < 4; ++it) {
            f16x4 v;
            v[0] = (_Float16)h[it].x; v[1] = (_Float16)h[it].y;
            v[2] = (_Float16)h[it].z; v[3] = (_Float16)h[it].w;
            *(f16x4*)(abase + buf * 8192 + aoff[it]) = v;
        }
    };

    f32x4 acc[4][4] = {};

    loadA(0, h0);
    stageB(0, 0);
    loadA(1, h1);
    writeA(h0, 0);
    __syncthreads();

    #pragma unroll
    for (int ks = 0; ks < NKS; ++ks) {
        const int buf = ks & 1;
        if (ks + 1 < NKS) stageB(ks + 1, buf ^ 1);
        if (ks + 2 < NKS) loadA(ks + 2, (ks & 1) ? h1 : h0);   // 2-deep prefetch

        #pragma unroll
        for (int kc = 0; kc < 2; ++kc) {
            f16x8 af[4], bf[4];
            #pragma unroll
            for (int mf = 0; mf < 4; ++mf)
                af[mf] = *(const f16x8*)&Asub[buf][kc * 8 + wm * 4 + mf][wl][0];
            #pragma unroll
            for (int nf = 0; nf < 4; ++nf)
                bf[nf] = *(const f16x8*)&Bsub[buf][kc * 16 + wn * 4 + nf][wl][0];
            #pragma unroll
            for (int mf = 0; mf < 4; ++mf)
                #pragma unroll
                for (int nf = 0; nf < 4; ++nf)
                    acc[mf][nf] = __builtin_amdgcn_mfma_f32_16x16x32_f16(
                        af[mf], bf[nf], acc[mf][nf], 0, 0, 0);
        }

        if (ks + 1 < NKS) writeA((ks & 1) ? h0 : h1, buf ^ 1);
        __syncthreads();
    }

    // ---- fused epilogue (D frag: col = lane&15, row = (lane>>4)*4 + r) ----
    if (wn == 0) {                       // k field: row-normalize over 64 cols
        #pragma unroll
        for (int mf = 0; mf < 4; ++mf) {
            f32x4 s = acc[mf][0] * acc[mf][0];
            #pragma unroll
            for (int nf = 1; nf < 4; ++nf) s += acc[mf][nf] * acc[mf][nf];
            #pragma unroll
            for (int r = 0; r < 4; ++r) {
                float t = s[r];
                t += __shfl_xor(t, 1); t += __shfl_xor(t, 2);
                t += __shfl_xor(t, 4); t += __shfl_xor(t, 8);
                const float sc = 1.f / (sqrtf(t) + EPS);
                #pragma unroll
                for (int nf = 0; nf < 4; ++nf) acc[mf][nf][r] *= sc;
            }
        }
    }
    if (wn == 3) {                       // beta field: sigmoid(acc + bias)
        #pragma unroll
        for (int nf = 0; nf < 4; ++nf) {
            const float bv = bb[nf * 16 + l15];
            #pragma unroll
            for (int mf = 0; mf < 4; ++mf)
                #pragma unroll
                for (int r = 0; r < 4; ++r)
                    acc[mf][nf][r] = 1.f / (1.f + __expf(-(acc[mf][nf][r] + bv)));
        }
    }

    #pragma unroll
    for (int mf = 0; mf < 4; ++mf)
        #pragma unroll
        for (int r = 0; r < 4; ++r) {
            float* dst = proj + (mbase + wm * 64 + mf * 16 + lr * 4 + r) * NFIELD
                              + wn * 64 + l15;
            dst[0]  = acc[mf][0][r];
            dst[16] = acc[mf][1][r];
            dst[32] = acc[mf][2][r];
            dst[48] = acc[mf][3][r];
        }
}

// ============================ kappa/kq precompute ============================
// kap2[t][b] = { <k_norm(t), k_norm(t+1)>  (0 if t+1>=T),
//                <k_norm(t), q(t)> }            -- both needed AT step t.
#define KAP_T 2112

__global__ __launch_bounds__(256) void kappa_kernel(
    const float* __restrict__ proj, float* __restrict__ kap2)
{
    const int tid = threadIdx.x;
    const int gid = blockIdx.x * 16 + (tid >> 4);   // one (t,b) per 16 lanes
    const int l   = tid & 15;
    const int t = gid >> 4, b = gid & 15;
    if (t >= T_STEPS) {
        if (l == 0) *(float2*)(kap2 + (size_t)gid * 2) = make_float2(0.f, 0.f);
        return;
    }
    const float* base = proj + ((size_t)t * BATCH + b) * NFIELD;
    const float4 k0 = *(const float4*)(base + 4 * l);           // k_norm(t)
    const float4 q0 = *(const float4*)(base + 128 + 4 * l);     // q(t)
    float cp = 0.f;
    float cq = 0.f;
    {
        float t0 = k0.x * q0.x; t0 = fmaf(k0.y, q0.y, t0);
        float t1 = k0.z * q0.z; t1 = fmaf(k0.w, q0.w, t1);
        cq = t0 + t1;
    }
    if (t + 1 < T_STEPS) {
        const float4 k1 = *(const float4*)(base + PROJ_TSTRIDE + 4 * l);
        float t0 = k0.x * k1.x; t0 = fmaf(k0.y, k1.y, t0);
        float t1 = k0.z * k1.z; t1 = fmaf(k0.w, k1.w, t1);
        cp = t0 + t1;
    }
    reduce16x2(cp, cq);
    if (l == 0) *(float2*)(kap2 + (size_t)gid * 2) = make_float2(cp, cq);
}

// ============================ sequential scan v8 ============================
// v7 + fix: consume slot j's registers BEFORE ldslot refills slot j.
// BOTH per-step dots read the entry state S(t-1) (one full step of slack)
// and are consumed only near the end of the step:
//   a(t+1)  = g(t)*<S(t-1),k(t+1)> + d(t)*kap(t+1)    (exact)
//   Sq(t)   = g(t)*<S(t-1),q(t)>   + d(t)*kq(t)       (exact)
// Carried chains: d->a->d (2 fma) and S->S (depth 2). The two DPP reduce
// chains are interleaved so neither exposes its dependency latency.

#define CH 32
#define NCHUNK (T_STEPS / CH)

__global__ __launch_bounds__(128) void scan_kernel(
    const float* __restrict__ proj,  // [T][B][256]
    const float* __restrict__ kap2,  // [KAP_T][B][2]
    const float* __restrict__ S0,    // [B][64][64]
    float* __restrict__ out,         // [T][B][64]  (silu applied at store)
    float* __restrict__ Sfin)        // [B][64][64]
{
    __shared__ float KQ[2][CH][128];   // [s][0:64)=kn, [64:128)=q   (32 KB)
    __shared__ float VG[2][CH][16];    // [s][2r]=v(i0+r), [s][2r+1]=g(i0+r)
    __shared__ float KP2[2][CH][2];    // [s] = {kap(t+1), kq(t)}

    const int tid = threadIdx.x;          // 0..127
    const int l   = tid & 15;
    const int grp = tid >> 4;             // 0..7 -> row within block
    const int b   = blockIdx.x >> 3;
    const int i0  = (blockIdx.x & 7) * 8;
    const int i   = i0 + grp;
    const int c0  = l * 4;

    const size_t srow = ((size_t)(b * 64 + i)) * 64 + c0;
    float4 S = *(const float4*)(S0 + srow);

    const float* pb = proj + (size_t)b * NFIELD;
    const int wid = tid >> 6, wl = tid & 63;

    // --- DMA address maps (constant per lane) ---
    const int l31  = wl & 31;
    const int kq_f = l31 * 4 + ((l31 >= 16) ? 64 : 0);
    const int kq_s = wl >> 5;
    const int idx  = wl & 15;
    const int vg_f = (idx & 1) ? (192 + i0 + (idx >> 1)) : (64 + i0 + (idx >> 1));
    const int vg_s = wl >> 4;

    auto stage = [&](int c, int nb) {
        const float* cbase = pb + (size_t)c * CH * PROJ_TSTRIDE;
        #pragma unroll
        for (int m = 0; m < 8; ++m) {                    // 16 KQ insts over 2 waves
            const int n = wid * 8 + m;
            const float* g = cbase + (size_t)(2 * n + kq_s) * PROJ_TSTRIDE + kq_f;
            void* lp = (char*)&KQ[nb][0][0] + n * 1024;
            __builtin_amdgcn_global_load_lds((const AS1 void*)g, (AS3 void*)lp, 16, 0, 0);
        }
        #pragma unroll
        for (int m = 0; m < 4; ++m) {                    // 8 VG insts over 2 waves
            const int p = wid * 4 + m;
            const float* g = cbase + (size_t)(4 * p + vg_s) * PROJ_TSTRIDE + vg_f;
            void* lp = (char*)&VG[nb][0][0] + p * 256;
            __builtin_amdgcn_global_load_lds((const AS1 void*)g, (AS3 void*)lp, 4, 0, 0);
        }
        if (wid == 0) {                                  // {kap,kq} for 32 steps
            const float* g = kap2 + ((size_t)(c * CH + (wl >> 1)) * BATCH + b) * 2
                           + (wl & 1);
            void* lp = (char*)&KP2[nb][0][0];
            __builtin_amdgcn_global_load_lds((const AS1 void*)g, (AS3 void*)lp, 4, 0, 0);
        }
    };

    float4 kn_s[4], q_s[4];
    float2 vg_s4[4];
    auto ldslot = [&](int cb, int s, int j) {
        kn_s[j]  = *(const float4*)(&KQ[cb][s][c0]);
        q_s[j]   = *(const float4*)(&KQ[cb][s][64 + c0]);
        vg_s4[j] = *(const float2*)(&VG[cb][s][2 * grp]);
    };

    stage(0, 0);
    __syncthreads();                     // waits DMA (vmcnt) + all threads

    float a;
    auto prime = [&](int nb) {
        #pragma unroll
        for (int j = 0; j < 4; ++j) ldslot(nb, j, j);
        a = dot4r(S, kn_s[0]);           // full-dot re-anchor of carried a
    };
    prime(0);

    float osel = 0.f;

    for (int c = 0; c < NCHUNK; ++c) {
        const int cb = c & 1;
        const bool more = (c + 1 < NCHUNK);
        if (more) stage(c + 1, cb ^ 1);  // DMA in flight across this chunk

        #pragma unroll
        for (int s = 0; s < CH; ++s) {
            const int j = s & 3;

            // --- consume slot j FIRST (v7 bug: refill clobbered these) ---
            const float4 kn = kn_s[j], q = q_s[j];
            const float  v = vg_s4[j].x, g = vg_s4[j].y;
            const float4 knn = kn_s[(s + 1) & 3];              // k(t+1), other slot
            const float2 kk = *(const float2*)&KP2[cb][s][0];  // {kap(t+1), kq(t)}

            if (s + 4 < CH) ldslot(cb, s + 4, j);   // refill the slot just freed

            // --- both dots from ENTRY state S(t-1); interleaved DPP reduces ---
            float cq;
            {
                float t0 = S.x * q.x; t0 = fmaf(S.y, q.y, t0);
                float t1 = S.z * q.z; t1 = fmaf(S.w, q.w, t1);
                cq = t0 + t1;
            }
            float cp = 0.f;
            if (s + 1 < CH) {
                float t0 = S.x * knn.x; t0 = fmaf(S.y, knn.y, t0);
                float t1 = S.z * knn.z; t1 = fmaf(S.w, knn.w, t1);
                cp = t0 + t1;
            }
            reduce16x2(cp, cq);

            const float d = v - a;
            S.x = fmaf(d, kn.x, g * S.x);
            S.y = fmaf(d, kn.y, g * S.y);
            S.z = fmaf(d, kn.z, g * S.z);
            S.w = fmaf(d, kn.w, g * S.w);

            const float sq = fmaf(d, kk.y, g * cq);          // Sq(t), exact
            if (s + 1 < CH) a = fmaf(d, kk.x, g * cp);       // a(t+1), exact

            osel = ((s & 15) == l) ? sq : osel;
            if ((s & 15) == 15) {
                const float y = osel * osel / (1.f + __expf(-osel));  // fused silu
                const int tbase = c * CH + (s - 15);
                out[((size_t)(tbase + l) * BATCH + b) * 64 + i] = y;
            }
        }

        if (more) {
            __syncthreads();             // next chunk's DMA complete
            prime(cb ^ 1);               // re-anchor a with a full dot
        }
    }

    *(float4*)(Sfin + srow) = S;
}

// ================================ launch ================================
extern "C" void kernel_launch(void* const* d_in, const int* in_sizes, int n_in,
                              void* d_out, int out_size, void* d_ws, size_t ws_size,
                              hipStream_t stream) {
    const float* x  = (const float*)d_in[0];
    const float* S0 = (const float*)d_in[1];
    const float* Wk = (const float*)d_in[2];
    const float* Wv = (const float*)d_in[3];
    const float* Wq = (const float*)d_in[4];
    const float* Wb = (const float*)d_in[5];
    const float* bb = (const float*)d_in[6];

    float* out  = (float*)d_out;                               // [T][B][64]
    float* Sfin = out + (size_t)T_STEPS * BATCH * NSTATE;      // [B][64][64]

    float*    proj = (float*)d_ws;                             // 33.55 MB
    float*    kap2 = proj + (size_t)T_STEPS * BATCH * NFIELD;  // 270 KB
    _Float16* W16  = (_Float16*)(kap2 + (size_t)KAP_T * BATCH * 2); // 512 KB

    prep_w16<<<128, 256, 0, stream>>>(Wk, Wv, Wq, Wb, W16);
    proj_mfma<<<(T_STEPS * BATCH) / PBM, 512, 0, stream>>>(x, W16, bb, proj);
    kappa_kernel<<<KAP_T, 256, 0, stream>>>(proj, kap2);
    scan_kernel<<<(BATCH * NSTATE) / 8, 128, 0, stream>>>(proj, kap2, S0, out, Sfin);
}

// Round 6
// 416.274 us; speedup vs baseline: 1.3184x; 1.0151x over previous
//
#include <hip/hip_runtime.h>
#include <math.h>

#define T_STEPS 2048
#define BATCH   16
#define DIM     1024
#define NSTATE  64
#define NFIELD  256                      // per (t,b): [k_norm|v|q|g] x 64
#define PROJ_TSTRIDE (BATCH * NFIELD)    // 4096 floats per t
static constexpr float EPS = 1e-6f;

#define AS1 __attribute__((address_space(1)))
#define AS3 __attribute__((address_space(3)))

typedef _Float16 f16x8 __attribute__((ext_vector_type(8)));
typedef _Float16 f16x4 __attribute__((ext_vector_type(4)));
typedef float    f32x4 __attribute__((ext_vector_type(4)));

// ===================== cross-lane helpers (16-lane reduce) =====================
template <int CTRL>
__device__ __forceinline__ float dpp_add(float x) {
    int yi = __builtin_amdgcn_update_dpp(0, __float_as_int(x), CTRL, 0xF, 0xF, true);
    return x + __int_as_float(yi);
}
__device__ __forceinline__ float reduce16(float x) {
    x = dpp_add<0x121>(x);   // row_ror:1
    x = dpp_add<0x122>(x);   // row_ror:2
    x = dpp_add<0x124>(x);   // row_ror:4
    x = dpp_add<0x128>(x);   // row_ror:8
    return x;
}
// interleaved dual reduce: the two DPP chains fill each other's dep gaps
__device__ __forceinline__ void reduce16x2(float& x, float& y) {
    x = dpp_add<0x121>(x); y = dpp_add<0x121>(y);
    x = dpp_add<0x122>(x); y = dpp_add<0x122>(y);
    x = dpp_add<0x124>(x); y = dpp_add<0x124>(y);
    x = dpp_add<0x128>(x); y = dpp_add<0x128>(y);
}
__device__ __forceinline__ float dotp(const float4& u, const float4& w) {
    float t0 = u.x * w.x; t0 = fmaf(u.y, w.y, t0);
    float t1 = u.z * w.z; t1 = fmaf(u.w, w.w, t1);
    return t0 + t1;
}
__device__ __forceinline__ float dot4r(const float4& u, const float4& w) {
    return reduce16(dotp(u, w));
}

// ========================= projection GEMM (fp16 MFMA) =========================
// Block tile 128x256, 8 waves (2m x 4n), wave tile 64x64, mfma 16x16x32_f16.
// LDS fragment-linear (lane*16B b128, conflict-free). B via global_load_lds DMA
// of pre-converted fragment-ordered fp16 weights. A: coalesced fp32 loads,
// 2 K-iterations deep (reg double-buffer h0/h1). K-loop fully unrolled.
// __launch_bounds__(512, 1): needs ~150 VGPR (acc 64 + frags + prefetch);
// a default 128-cap would spill acc in the K-loop.

#define PBM   128
#define KSTEP 64
#define NKS   (DIM / KSTEP)   // 16

__global__ __launch_bounds__(256) void prep_w16(
    const float* __restrict__ Wk, const float* __restrict__ Wv,
    const float* __restrict__ Wq, const float* __restrict__ Wb,
    _Float16* __restrict__ W16)
{
    const int flat = blockIdx.x * 256 + threadIdx.x;   // 16*32*64 = 32768
    const int lane = flat & 63;
    const int st   = (flat >> 6) & 31;
    const int ks   = flat >> 11;
    const int cg = st & 15, kc2 = st >> 4;
    const int col = cg * 16 + (lane & 15);
    const int field = col >> 6, wrow = col & 63;
    const float* Wf = (field == 0 ? Wk : field == 1 ? Wv : field == 2 ? Wq : Wb);
    const float* src = Wf + (size_t)wrow * DIM + ks * 64 + kc2 * 32 + (lane >> 4) * 8;
    const float4 a = *(const float4*)(src);
    const float4 b = *(const float4*)(src + 4);
    f16x8 r;
    r[0] = (_Float16)a.x; r[1] = (_Float16)a.y; r[2] = (_Float16)a.z; r[3] = (_Float16)a.w;
    r[4] = (_Float16)b.x; r[5] = (_Float16)b.y; r[6] = (_Float16)b.z; r[7] = (_Float16)b.w;
    *(f16x8*)(W16 + (size_t)flat * 8) = r;
}

__global__ __launch_bounds__(512, 1) void proj_mfma(
    const float* __restrict__ x, const _Float16* __restrict__ W16,
    const float* __restrict__ bb, float* __restrict__ proj)
{
    __shared__ _Float16 Asub[2][16][64][8];   // 16KB/buf
    __shared__ _Float16 Bsub[2][32][64][8];   // 32KB/buf

    const int tid = threadIdx.x;
    const int w = tid >> 6, wl = tid & 63;
    const int wm = w >> 2, wn = w & 3;
    const int l15 = wl & 15, lr = wl >> 4;
    const size_t mbase = (size_t)blockIdx.x * PBM;

    _Float16* const abase = &Asub[0][0][0][0];
    _Float16* const bbase = &Bsub[0][0][0][0];

    // ---- A staging map: 4 float4/thread, fully coalesced ----
    const float* asrc[4];
    int aoff[4];
    #pragma unroll
    for (int it = 0; it < 4; ++it) {
        const int fid = it * 512 + tid;
        const int row = fid >> 4, kq = (fid & 15) * 4;
        asrc[it] = x + (mbase + row) * (size_t)DIM + kq;
        aoff[it] = ((kq >> 5) * 8 + (row >> 4)) * 512
                 + ((row & 15) + ((kq >> 3) & 3) * 16) * 8
                 + (kq & 7);
    }
    // ---- B staging map: 4 global_load_lds per wave (st wave-uniform) ----
    const _Float16* bsrc[4];
    int boff[4];
    #pragma unroll
    for (int m = 0; m < 4; ++m) {
        const int st = w * 4 + m;
        bsrc[m] = W16 + ((size_t)st * 64 + wl) * 8;
        boff[m] = st * 512;
    }

    auto stageB = [&](int ks, int buf) {
        #pragma unroll
        for (int m = 0; m < 4; ++m) {
            const _Float16* g = bsrc[m] + (size_t)ks * 16384;
            void* lp = (char*)bbase + (size_t)(buf * 16384 + boff[m]) * 2;
            __builtin_amdgcn_global_load_lds((const AS1 void*)g, (AS3 void*)lp, 16, 0, 0);
        }
    };

    float4 h0[4], h1[4];
    auto loadA = [&](int ks, float4* h) {
        #pragma unroll
        for (int it = 0; it < 4; ++it)
            h[it] = *(const float4*)(asrc[it] + ks * KSTEP);
    };
    auto writeA = [&](const float4* h, int buf) {
        #pragma unroll
        for (int it = 0; it < 4; ++it) {
            f16x4 v;
            v[0] = (_Float16)h[it].x; v[1] = (_Float16)h[it].y;
            v[2] = (_Float16)h[it].z; v[3] = (_Float16)h[it].w;
            *(f16x4*)(abase + buf * 8192 + aoff[it]) = v;
        }
    };

    f32x4 acc[4][4] = {};

    loadA(0, h0);
    stageB(0, 0);
    loadA(1, h1);
    writeA(h0, 0);
    __syncthreads();

    #pragma unroll
    for (int ks = 0; ks < NKS; ++ks) {
        const int buf = ks & 1;
        if (ks + 1 < NKS) stageB(ks + 1, buf ^ 1);
        if (ks + 2 < NKS) loadA(ks + 2, (ks & 1) ? h1 : h0);   // 2-deep prefetch

        #pragma unroll
        for (int kc = 0; kc < 2; ++kc) {
            f16x8 af[4], bf[4];
            #pragma unroll
            for (int mf = 0; mf < 4; ++mf)
                af[mf] = *(const f16x8*)&Asub[buf][kc * 8 + wm * 4 + mf][wl][0];
            #pragma unroll
            for (int nf = 0; nf < 4; ++nf)
                bf[nf] = *(const f16x8*)&Bsub[buf][kc * 16 + wn * 4 + nf][wl][0];
            #pragma unroll
            for (int mf = 0; mf < 4; ++mf)
                #pragma unroll
                for (int nf = 0; nf < 4; ++nf)
                    acc[mf][nf] = __builtin_amdgcn_mfma_f32_16x16x32_f16(
                        af[mf], bf[nf], acc[mf][nf], 0, 0, 0);
        }

        if (ks + 1 < NKS) writeA((ks & 1) ? h0 : h1, buf ^ 1);
        __syncthreads();
    }

    // ---- fused epilogue (D frag: col = lane&15, row = (lane>>4)*4 + r) ----
    if (wn == 0) {                       // k field: row-normalize over 64 cols
        #pragma unroll
        for (int mf = 0; mf < 4; ++mf) {
            f32x4 s = acc[mf][0] * acc[mf][0];
            #pragma unroll
            for (int nf = 1; nf < 4; ++nf) s += acc[mf][nf] * acc[mf][nf];
            #pragma unroll
            for (int r = 0; r < 4; ++r) {
                float t = s[r];
                t += __shfl_xor(t, 1); t += __shfl_xor(t, 2);
                t += __shfl_xor(t, 4); t += __shfl_xor(t, 8);
                const float sc = 1.f / (sqrtf(t) + EPS);
                #pragma unroll
                for (int nf = 0; nf < 4; ++nf) acc[mf][nf][r] *= sc;
            }
        }
    }
    if (wn == 3) {                       // beta field: sigmoid(acc + bias)
        #pragma unroll
        for (int nf = 0; nf < 4; ++nf) {
            const float bv = bb[nf * 16 + l15];
            #pragma unroll
            for (int mf = 0; mf < 4; ++mf)
                #pragma unroll
                for (int r = 0; r < 4; ++r)
                    acc[mf][nf][r] = 1.f / (1.f + __expf(-(acc[mf][nf][r] + bv)));
        }
    }

    #pragma unroll
    for (int mf = 0; mf < 4; ++mf)
        #pragma unroll
        for (int r = 0; r < 4; ++r) {
            float* dst = proj + (mbase + wm * 64 + mf * 16 + lr * 4 + r) * NFIELD
                              + wn * 64 + l15;
            dst[0]  = acc[mf][0][r];
            dst[16] = acc[mf][1][r];
            dst[32] = acc[mf][2][r];
            dst[48] = acc[mf][3][r];
        }
}

// ============================ kappa/kq precompute ============================
// kap2[t][b] = { <k_norm(t), k_norm(t+1)>  (0 if t+1>=T),
//                <k_norm(t), q(t)> }            -- both needed AT step t.
#define KAP_T 2112

__global__ __launch_bounds__(256) void kappa_kernel(
    const float* __restrict__ proj, float* __restrict__ kap2)
{
    const int tid = threadIdx.x;
    const int gid = blockIdx.x * 16 + (tid >> 4);   // one (t,b) per 16 lanes
    const int l   = tid & 15;
    const int t = gid >> 4, b = gid & 15;
    if (t >= T_STEPS) {
        if (l == 0) *(float2*)(kap2 + (size_t)gid * 2) = make_float2(0.f, 0.f);
        return;
    }
    const float* base = proj + ((size_t)t * BATCH + b) * NFIELD;
    const float4 k0 = *(const float4*)(base + 4 * l);           // k_norm(t)
    const float4 q0 = *(const float4*)(base + 128 + 4 * l);     // q(t)
    float cp = 0.f;
    float cq = dotp(k0, q0);
    if (t + 1 < T_STEPS) {
        const float4 k1 = *(const float4*)(base + PROJ_TSTRIDE + 4 * l);
        cp = dotp(k0, k1);
    }
    reduce16x2(cp, cq);
    if (l == 0) *(float2*)(kap2 + (size_t)gid * 2) = make_float2(cp, cq);
}

// ============================ sequential scan v9 ============================
// Cross-step software pipeline, explicit in source:
//   entering step s: a = <S(s-1),k(s)>, cqr = <S(s-1),q(s)>, cpr = <S(s-1),k(s+1)>
//   body: d = v-a; sq = g*cqr + d*kq0(s); a' = g*cpr + d*kap1(s); S = g*S + d*k
//         then compute NEXT step's partials+reduce from the fresh S -> cqr,cpr.
// The DPP reduce has one full period to complete before its results are read.
// kk ({kap1,kq0}) prefetched 4 steps ahead into registers like the other slots.
// __launch_bounds__(128, 1): 1 wave/SIMD regardless; free the VGPR budget so
// the scheduler can hold the pipelined state (old 88-reg cap blocked this).

#define CH 32
#define NCHUNK (T_STEPS / CH)

__global__ __launch_bounds__(128, 1) void scan_kernel(
    const float* __restrict__ proj,  // [T][B][256]
    const float* __restrict__ kap2,  // [KAP_T][B][2]
    const float* __restrict__ S0,    // [B][64][64]
    float* __restrict__ out,         // [T][B][64]  (silu applied at store)
    float* __restrict__ Sfin)        // [B][64][64]
{
    __shared__ float KQ[2][CH][128];   // [s][0:64)=kn, [64:128)=q   (32 KB)
    __shared__ float VG[2][CH][16];    // [s][2r]=v(i0+r), [s][2r+1]=g(i0+r)
    __shared__ float KP2[2][CH][2];    // [s] = {kap1(s), kq0(s)}

    const int tid = threadIdx.x;          // 0..127
    const int l   = tid & 15;
    const int grp = tid >> 4;             // 0..7 -> row within block
    const int b   = blockIdx.x >> 3;
    const int i0  = (blockIdx.x & 7) * 8;
    const int i   = i0 + grp;
    const int c0  = l * 4;

    const size_t srow = ((size_t)(b * 64 + i)) * 64 + c0;
    float4 S = *(const float4*)(S0 + srow);

    const float* pb = proj + (size_t)b * NFIELD;
    const int wid = tid >> 6, wl = tid & 63;

    // --- DMA address maps (constant per lane) ---
    const int l31  = wl & 31;
    const int kq_f = l31 * 4 + ((l31 >= 16) ? 64 : 0);
    const int kq_s = wl >> 5;
    const int idx  = wl & 15;
    const int vg_f = (idx & 1) ? (192 + i0 + (idx >> 1)) : (64 + i0 + (idx >> 1));
    const int vg_s = wl >> 4;

    auto stage = [&](int c, int nb) {
        const float* cbase = pb + (size_t)c * CH * PROJ_TSTRIDE;
        #pragma unroll
        for (int m = 0; m < 8; ++m) {                    // 16 KQ insts over 2 waves
            const int n = wid * 8 + m;
            const float* g = cbase + (size_t)(2 * n + kq_s) * PROJ_TSTRIDE + kq_f;
            void* lp = (char*)&KQ[nb][0][0] + n * 1024;
            __builtin_amdgcn_global_load_lds((const AS1 void*)g, (AS3 void*)lp, 16, 0, 0);
        }
        #pragma unroll
        for (int m = 0; m < 4; ++m) {                    // 8 VG insts over 2 waves
            const int p = wid * 4 + m;
            const float* g = cbase + (size_t)(4 * p + vg_s) * PROJ_TSTRIDE + vg_f;
            void* lp = (char*)&VG[nb][0][0] + p * 256;
            __builtin_amdgcn_global_load_lds((const AS1 void*)g, (AS3 void*)lp, 4, 0, 0);
        }
        if (wid == 0) {                                  // {kap1,kq0} for 32 steps
            const float* g = kap2 + ((size_t)(c * CH + (wl >> 1)) * BATCH + b) * 2
                           + (wl & 1);
            void* lp = (char*)&KP2[nb][0][0];
            __builtin_amdgcn_global_load_lds((const AS1 void*)g, (AS3 void*)lp, 4, 0, 0);
        }
    };

    float4 kn_s[4], q_s[4];
    float2 vg_s4[4], kk_s[4];
    auto ldslot = [&](int cb2, int s, int j) {
        kn_s[j]  = *(const float4*)(&KQ[cb2][s][c0]);
        q_s[j]   = *(const float4*)(&KQ[cb2][s][64 + c0]);
        vg_s4[j] = *(const float2*)(&VG[cb2][s][2 * grp]);
        kk_s[j]  = *(const float2*)(&KP2[cb2][s][0]);
    };

    stage(0, 0);
    __syncthreads();                     // waits DMA (vmcnt) + all threads

    float a, cqr, cpr;
    auto prime = [&](int nb) {
        #pragma unroll
        for (int j = 0; j < 4; ++j) ldslot(nb, j, j);
        float aP  = dotp(S, kn_s[0]);    // a(0)   = <S, k(0)>
        float cqP = dotp(S, q_s[0]);     // cqr(0) = <S, q(0)>
        float cpP = dotp(S, kn_s[1]);    // cpr(0) = <S, k(1)>
        reduce16x2(aP, cqP);
        cpP = reduce16(cpP);
        a = aP; cqr = cqP; cpr = cpP;
    };
    prime(0);

    float osel = 0.f;

    for (int c = 0; c < NCHUNK; ++c) {
        const int cb = c & 1;
        const bool more = (c + 1 < NCHUNK);
        if (more) stage(c + 1, cb ^ 1);  // DMA in flight across this chunk

        #pragma unroll
        for (int s = 0; s < CH; ++s) {
            const int j = s & 3;

            const float4 kn = kn_s[j];
            const float  v = vg_s4[j].x, g = vg_s4[j].y;
            const float2 kk = kk_s[j];   // {kap1(s)=<k(s),k(s+1)>, kq0(s)=<k(s),q(s)>}

            // --- consume pipelined values: pure 2-fma chains ---
            const float d  = v - a;
            const float sq = fmaf(d, kk.y, g * cqr);   // Sq(s), exact
            const float an = fmaf(d, kk.x, g * cpr);   // a(s+1), exact

            S.x = fmaf(d, kn.x, g * S.x);
            S.y = fmaf(d, kn.y, g * S.y);
            S.z = fmaf(d, kn.z, g * S.z);
            S.w = fmaf(d, kn.w, g * S.w);

            if (s + 4 < CH) ldslot(cb, s + 4, j);   // refill after slot consumed

            // --- NEXT step's dots from fresh S; reduce has a full period ---
            if (s + 2 < CH) {
                float cqP = dotp(S, q_s[(s + 1) & 3]);     // <S(s), q(s+1)>
                float cpP = dotp(S, kn_s[(s + 2) & 3]);    // <S(s), k(s+2)>
                reduce16x2(cpP, cqP);
                cpr = cpP; cqr = cqP;
            } else if (s + 1 < CH) {                       // s == CH-2
                cqr = reduce16(dotp(S, q_s[(s + 1) & 3]));
            }                                              // s == CH-1: prime redoes
            a = an;

            osel = ((s & 15) == l) ? sq : osel;
            if ((s & 15) == 15) {
                const float y = osel * osel / (1.f + __expf(-osel));  // fused silu
                const int tbase = c * CH + (s - 15);
                out[((size_t)(tbase + l) * BATCH + b) * 64 + i] = y;
            }
        }

        if (more) {
            __syncthreads();             // next chunk's DMA complete
            prime(cb ^ 1);               // re-derive a, cqr, cpr from fresh slots
        }
    }

    *(float4*)(Sfin + srow) = S;
}

// ================================ launch ================================
extern "C" void kernel_launch(void* const* d_in, const int* in_sizes, int n_in,
                              void* d_out, int out_size, void* d_ws, size_t ws_size,
                              hipStream_t stream) {
    const float* x  = (const float*)d_in[0];
    const float* S0 = (const float*)d_in[1];
    const float* Wk = (const float*)d_in[2];
    const float* Wv = (const float*)d_in[3];
    const float* Wq = (const float*)d_in[4];
    const float* Wb = (const float*)d_in[5];
    const float* bb = (const float*)d_in[6];

    float* out  = (float*)d_out;                               // [T][B][64]
    float* Sfin = out + (size_t)T_STEPS * BATCH * NSTATE;      // [B][64][64]

    float*    proj = (float*)d_ws;                             // 33.55 MB
    float*    kap2 = proj + (size_t)T_STEPS * BATCH * NFIELD;  // 270 KB
    _Float16* W16  = (_Float16*)(kap2 + (size_t)KAP_T * BATCH * 2); // 512 KB

    prep_w16<<<128, 256, 0, stream>>>(Wk, Wv, Wq, Wb, W16);
    proj_mfma<<<(T_STEPS * BATCH) / PBM, 512, 0, stream>>>(x, W16, bb, proj);
    kappa_kernel<<<KAP_T, 256, 0, stream>>>(proj, kap2);
    scan_kernel<<<(BATCH * NSTATE) / 8, 128, 0, stream>>>(proj, kap2, S0, out, Sfin);
}